// Round 6
// baseline (956.389 us; speedup 1.0000x reference)
//
#include <hip/hip_runtime.h>

// 8 bf16 in 4 VGPRs (guide-verified frag type for mfma_f32_16x16x32_bf16)
typedef short s8v __attribute__((ext_vector_type(8)));
typedef float f4v __attribute__((ext_vector_type(4)));

__device__ __forceinline__ float bf2f(short s) {
    union { unsigned u; float f; } c;
    c.u = ((unsigned)(unsigned short)s) << 16;
    return c.f;
}
__device__ __forceinline__ short f2bf(float f) {
    union { float f; unsigned u; } c; c.f = f;
    unsigned r = (c.u + 0x7FFFu + ((c.u >> 16) & 1u)) >> 16;
    return (short)r;
}
// convert 8 contiguous fp32 -> 8 bf16 (two float4 loads, 32B/lane, coalesced)
__device__ __forceinline__ s8v cvt8(const float* __restrict__ p) {
    f4v a = *(const f4v*)p;
    f4v b = *(const f4v*)(p + 4);
    s8v r;
    r[0] = f2bf(a[0]); r[1] = f2bf(a[1]); r[2] = f2bf(a[2]); r[3] = f2bf(a[3]);
    r[4] = f2bf(b[0]); r[5] = f2bf(b[1]); r[6] = f2bf(b[2]); r[7] = f2bf(b[3]);
    return r;
}

// ------------- GEMM: A (M x K, stride lda; fp32 or bf16), B (K x N fp32 native),
// ------------- C (M x N, stride ldc; bf16 or fp32). 128x128 tile, BK=32,
// ------------- 256 thr = 4 waves, wave = 64x64 via 4x4 16x16x32 MFMAs.
// B is transposed during LDS staging (scatter ds_write_b16) with fp32->bf16 cvt.
template <bool AF32, bool CF32>
__global__ __launch_bounds__(256) void gemm_bn(const void* __restrict__ Av,
                                               const float* __restrict__ B,
                                               void* __restrict__ Cv,
                                               int K, int N, int lda, int ldc) {
    __shared__ __align__(16) short As[128 * 40];
    __shared__ __align__(16) short Bs[128 * 40];   // [n][k] transposed
    const int tid = threadIdx.x;
    const int lane = tid & 63;
    const int wave = tid >> 6;
    const int quad = lane >> 4;
    const int l15 = lane & 15;
    const int m0 = blockIdx.y * 128;
    const int n0 = blockIdx.x * 128;
    const int wm = (wave & 1) * 64;
    const int wn = (wave >> 1) * 64;

    f4v acc[4][4];
#pragma unroll
    for (int i = 0; i < 4; i++)
#pragma unroll
        for (int j = 0; j < 4; j++) acc[i][j] = (f4v){0.f, 0.f, 0.f, 0.f};

    const int ar0 = tid >> 2, akc0 = (tid & 3) * 8;
    const int ar1 = (tid + 256) >> 2, akc1 = ((tid + 256) & 3) * 8;
    const int bk0 = tid >> 4, bnc0 = (tid & 15) * 8;
    const int bk1 = (tid + 256) >> 4, bnc1 = ((tid + 256) & 15) * 8;

    for (int k0 = 0; k0 < K; k0 += 32) {
        __syncthreads();
        if (AF32) {
            const float* A = (const float*)Av;
            *(s8v*)(&As[ar0 * 40 + akc0]) = cvt8(&A[(long)(m0 + ar0) * lda + k0 + akc0]);
            *(s8v*)(&As[ar1 * 40 + akc1]) = cvt8(&A[(long)(m0 + ar1) * lda + k0 + akc1]);
        } else {
            const short* A = (const short*)Av;
            *(s8v*)(&As[ar0 * 40 + akc0]) = *(const s8v*)(&A[(long)(m0 + ar0) * lda + k0 + akc0]);
            *(s8v*)(&As[ar1 * 40 + akc1]) = *(const s8v*)(&A[(long)(m0 + ar1) * lda + k0 + akc1]);
        }
        s8v b0 = cvt8(&B[(long)(k0 + bk0) * N + n0 + bnc0]);
        s8v b1 = cvt8(&B[(long)(k0 + bk1) * N + n0 + bnc1]);
#pragma unroll
        for (int i = 0; i < 8; i++) Bs[(bnc0 + i) * 40 + bk0] = b0[i];
#pragma unroll
        for (int i = 0; i < 8; i++) Bs[(bnc1 + i) * 40 + bk1] = b1[i];
        __syncthreads();
        s8v af[4], bfr[4];
#pragma unroll
        for (int mi = 0; mi < 4; mi++)
            af[mi] = *(const s8v*)(&As[(wm + mi * 16 + l15) * 40 + quad * 8]);
#pragma unroll
        for (int ni = 0; ni < 4; ni++)
            bfr[ni] = *(const s8v*)(&Bs[(wn + ni * 16 + l15) * 40 + quad * 8]);
#pragma unroll
        for (int mi = 0; mi < 4; mi++)
#pragma unroll
            for (int ni = 0; ni < 4; ni++)
                acc[mi][ni] = __builtin_amdgcn_mfma_f32_16x16x32_bf16(af[mi], bfr[ni], acc[mi][ni], 0, 0, 0);
    }
#pragma unroll
    for (int mi = 0; mi < 4; mi++)
#pragma unroll
        for (int ni = 0; ni < 4; ni++)
#pragma unroll
            for (int r = 0; r < 4; r++) {
                int row = m0 + wm + mi * 16 + quad * 4 + r;
                int col = n0 + wn + ni * 16 + l15;
                if (CF32) ((float*)Cv)[(long)row * ldc + col] = acc[mi][ni][r];
                else      ((short*)Cv)[(long)row * ldc + col] = f2bf(acc[mi][ni][r]);
            }
}

// ---------------- RoPE in-place on qkv cols [0, 2560) ----------------
// qkv: (4096 rows) x 3072 bf16; 40 heads (32 q + 8 k) x 64 dims; pair (j, j+32)
__global__ __launch_bounds__(256) void rope_kernel(short* __restrict__ qkv) {
    int tid = blockIdx.x * 256 + threadIdx.x; // 0 .. 4096*1280-1
    int p = tid % 1280;
    int row = tid / 1280;
    int head = p >> 5;
    int j = p & 31;
    int s = row & 2047;
    int c1 = head * 64 + j;
    float freq = exp2f(-(float)j * 0.4152410118609203f); // log2(10000)/32
    float ang = (float)s * freq;
    float sn, cs;
    sincosf(ang, &sn, &cs);
    long base = (long)row * 3072;
    float x1 = bf2f(qkv[base + c1]);
    float x2 = bf2f(qkv[base + c1 + 32]);
    qkv[base + c1]      = f2bf(x1 * cs - x2 * sn);
    qkv[base + c1 + 32] = f2bf(x2 * cs + x1 * sn);
}

// ---------------- flash attention (MFMA; validated bf16-identical to the
// ---------------- scalar reference implementation in rounds 3/4) ----------------
// grid (32 q-tiles, 32 heads, 2 batch), 256 thr = 4 waves; wave owns 16 q-rows.
// KV tile = 64 keys. Output written in-place into qkv's q-columns (race-free:
// each block reads its own Q exactly once, before the KV loop).
__global__ __launch_bounds__(256) void attn_kernel(short* __restrict__ qkv) {
    __shared__ __align__(16) short Qs[64 * 72];
    __shared__ __align__(16) short Ks[64 * 72];
    __shared__ __align__(16) short Vt[64 * 72];     // [d][key], key-chunk swizzled
    __shared__ __align__(16) short Ps[4][16 * 72];  // per-wave P, key-chunk swizzled

    const int tid = threadIdx.x;
    const int lane = tid & 63;
    const int wave = tid >> 6;
    const int quad = lane >> 4;
    const int l15 = lane & 15;
    const int b = blockIdx.z;
    const int h = blockIdx.y;
    const int kvh = h >> 2;
    const int q0 = blockIdx.x * 64;

    const long qbase = ((long)b * 2048 + q0) * 3072 + h * 64;
    const long kbase = ((long)b * 2048) * 3072 + 2048 + kvh * 64;
    const long vbase = kbase + 512;

#pragma unroll
    for (int cc = 0; cc < 2; cc++) {
        int ch = tid + cc * 256;
        int r = ch >> 3, d0 = (ch & 7) * 8;
        *(s8v*)(&Qs[r * 72 + d0]) = *(const s8v*)(&qkv[qbase + (long)r * 3072 + d0]);
    }
    __syncthreads();
    s8v qf[2];
    qf[0] = *(const s8v*)(&Qs[(wave * 16 + l15) * 72 + quad * 8]);
    qf[1] = *(const s8v*)(&Qs[(wave * 16 + l15) * 72 + 32 + quad * 8]);

    float m_i[4], l_i[4];
    f4v o[4];
#pragma unroll
    for (int r = 0; r < 4; r++) { m_i[r] = -1e30f; l_i[r] = 0.0f; }
#pragma unroll
    for (int ni = 0; ni < 4; ni++) o[ni] = (f4v){0.f, 0.f, 0.f, 0.f};

    for (int kt = 0; kt < 2048; kt += 64) {
        __syncthreads();
#pragma unroll
        for (int cc = 0; cc < 2; cc++) {
            int ch = tid + cc * 256;
            int r = ch >> 3, d0 = (ch & 7) * 8;
            *(s8v*)(&Ks[r * 72 + d0]) = *(const s8v*)(&qkv[kbase + (long)(kt + r) * 3072 + d0]);
            s8v v = *(const s8v*)(&qkv[vbase + (long)(kt + r) * 3072 + d0]);
            int g = d0 >> 3;
            int chn = ((r >> 3) ^ g) * 8 + (r & 7);
#pragma unroll
            for (int i = 0; i < 8; i++) Vt[(d0 + i) * 72 + chn] = v[i];
        }
        __syncthreads();

        // QK^T: scores for this wave's 16 rows x 64 keys
        f4v sc[4];
#pragma unroll
        for (int ni = 0; ni < 4; ni++) {
            s8v kf0 = *(const s8v*)(&Ks[(ni * 16 + l15) * 72 + quad * 8]);
            s8v kf1 = *(const s8v*)(&Ks[(ni * 16 + l15) * 72 + 32 + quad * 8]);
            f4v a = (f4v){0.f, 0.f, 0.f, 0.f};
            a = __builtin_amdgcn_mfma_f32_16x16x32_bf16(qf[0], kf0, a, 0, 0, 0);
            a = __builtin_amdgcn_mfma_f32_16x16x32_bf16(qf[1], kf1, a, 0, 0, 0);
            sc[ni] = a * 0.125f; // 1/sqrt(64)
        }
        // online softmax per row (row = quad*4 + r; 16 lanes/quad hold the keys)
        float alpha[4], rs[4];
#pragma unroll
        for (int r = 0; r < 4; r++) {
            float v = fmaxf(fmaxf(sc[0][r], sc[1][r]), fmaxf(sc[2][r], sc[3][r]));
            v = fmaxf(v, __shfl_xor(v, 1));
            v = fmaxf(v, __shfl_xor(v, 2));
            v = fmaxf(v, __shfl_xor(v, 4));
            v = fmaxf(v, __shfl_xor(v, 8));
            float mn = fmaxf(m_i[r], v);
            alpha[r] = __expf(m_i[r] - mn);
            m_i[r] = mn;
            rs[r] = 0.f;
        }
#pragma unroll
        for (int ni = 0; ni < 4; ni++)
#pragma unroll
            for (int r = 0; r < 4; r++) {
                float pv = __expf(sc[ni][r] - m_i[r]);
                sc[ni][r] = pv;
                rs[r] += pv;
            }
#pragma unroll
        for (int r = 0; r < 4; r++) {
            float v = rs[r];
            v += __shfl_xor(v, 1);
            v += __shfl_xor(v, 2);
            v += __shfl_xor(v, 4);
            v += __shfl_xor(v, 8);
            l_i[r] = l_i[r] * alpha[r] + v;
        }
        // P (C-layout) -> LDS (row-major, key-chunk swizzled)
#pragma unroll
        for (int ni = 0; ni < 4; ni++)
#pragma unroll
            for (int r = 0; r < 4; r++) {
                int row = quad * 4 + r;
                int key = ni * 16 + l15;
                int chn = ((key >> 3) ^ (row >> 3)) * 8 + (key & 7);
                Ps[wave][row * 72 + chn] = f2bf(sc[ni][r]);
            }
        __syncthreads();
        // rescale O
#pragma unroll
        for (int ni = 0; ni < 4; ni++) {
            f4v t = o[ni];
            t[0] *= alpha[0]; t[1] *= alpha[1]; t[2] *= alpha[2]; t[3] *= alpha[3];
            o[ni] = t;
        }
        // P in A-layout (m = l15 = q-row, k = keys)
        s8v pf0 = *(const s8v*)(&Ps[wave][l15 * 72 + ((quad ^ (l15 >> 3)) * 8)]);
        s8v pf1 = *(const s8v*)(&Ps[wave][l15 * 72 + (((4 + quad) ^ (l15 >> 3)) * 8)]);
#pragma unroll
        for (int ni = 0; ni < 4; ni++) {
            int d = ni * 16 + l15;
            s8v vf0 = *(const s8v*)(&Vt[d * 72 + ((quad ^ (d >> 3)) * 8)]);
            s8v vf1 = *(const s8v*)(&Vt[d * 72 + (((4 + quad) ^ (d >> 3)) * 8)]);
            o[ni] = __builtin_amdgcn_mfma_f32_16x16x32_bf16(pf0, vf0, o[ni], 0, 0, 0);
            o[ni] = __builtin_amdgcn_mfma_f32_16x16x32_bf16(pf1, vf1, o[ni], 0, 0, 0);
        }
    }
    // epilogue: O /= l, store in-place into qkv q-region (ld = 3072)
#pragma unroll
    for (int r = 0; r < 4; r++) {
        float inv = 1.0f / l_i[r];
        int srow = q0 + wave * 16 + quad * 4 + r;
        long obase = ((long)b * 2048 + srow) * 3072 + h * 64;
#pragma unroll
        for (int ni = 0; ni < 4; ni++)
            qkv[obase + ni * 16 + l15] = f2bf(o[ni][r] * inv);
    }
}

extern "C" void kernel_launch(void* const* d_in, const int* in_sizes, int n_in,
                              void* d_out, int out_size, void* d_ws, size_t ws_size,
                              hipStream_t stream) {
    (void)in_sizes; (void)n_in; (void)out_size; (void)ws_size;
    const float* x  = (const float*)d_in[0];   // (2,2048,2048) fp32
    const float* Wq = (const float*)d_in[1];   // (2048,2048) fp32
    const float* Wk = (const float*)d_in[2];   // (2048,512)  fp32
    const float* Wv = (const float*)d_in[3];   // (2048,512)  fp32
    const float* Wo = (const float*)d_in[4];   // (2048,2048) fp32

    short* qkv = (short*)d_ws;   // 4096 x 3072 bf16 = 25.2 MB (only ws use)

    // QKV projections (A = x fp32, C = bf16 strided into qkv)
    gemm_bn<true, false><<<dim3(16, 32), 256, 0, stream>>>(x, Wq, qkv,        2048, 2048, 2048, 3072);
    gemm_bn<true, false><<<dim3(4, 32), 256, 0, stream>>>(x, Wk, qkv + 2048, 2048,  512, 2048, 3072);
    gemm_bn<true, false><<<dim3(4, 32), 256, 0, stream>>>(x, Wv, qkv + 2560, 2048,  512, 2048, 3072);
    // RoPE on q,k (bf16 in-place)
    rope_kernel<<<dim3(20480), 256, 0, stream>>>(qkv);
    // attention: ctx written in-place into qkv q-columns
    attn_kernel<<<dim3(32, 32, 2), 256, 0, stream>>>(qkv);
    // output projection: A = qkv (bf16, lda=3072) x Wo (fp32) -> d_out as FP32
    gemm_bn<false, true><<<dim3(16, 32), 256, 0, stream>>>(qkv, Wo, d_out, 2048, 2048, 3072, 2048);
}

// Round 7
// 448.689 us; speedup vs baseline: 2.1315x; 2.1315x over previous
//
#include <hip/hip_runtime.h>

typedef short s8v __attribute__((ext_vector_type(8)));
typedef float f4v __attribute__((ext_vector_type(4)));

typedef const __attribute__((address_space(1))) char* gp1_t;
typedef __attribute__((address_space(3))) char* lp3_t;

__device__ __forceinline__ float bf2f(short s) {
    union { unsigned u; float f; } c;
    c.u = ((unsigned)(unsigned short)s) << 16;
    return c.f;
}
__device__ __forceinline__ short f2bf(float f) {
    union { float f; unsigned u; } c; c.f = f;
    unsigned r = (c.u + 0x7FFFu + ((c.u >> 16) & 1u)) >> 16;
    return (short)r;
}
__device__ __forceinline__ s8v cvt8(const float* __restrict__ p) {
    f4v a = *(const f4v*)p;
    f4v b = *(const f4v*)(p + 4);
    s8v r;
    r[0] = f2bf(a[0]); r[1] = f2bf(a[1]); r[2] = f2bf(a[2]); r[3] = f2bf(a[3]);
    r[4] = f2bf(b[0]); r[5] = f2bf(b[1]); r[6] = f2bf(b[2]); r[7] = f2bf(b[3]);
    return r;
}

// ======================= FAST PATH (ws >= 64 MiB) =======================

// fp32 -> bf16 straight copy (x)
__global__ __launch_bounds__(256) void cvt_x(const float* __restrict__ x,
                                             short* __restrict__ xb) {
    long i = ((long)blockIdx.x * 256 + threadIdx.x) * 8;
    *(s8v*)&xb[i] = cvt8(&x[i]);
}

// W (2048 x N fp32) -> Wt rows [obase+n][k] bf16 (ld 2048)
__global__ __launch_bounds__(256) void cvt_wt(const float* __restrict__ W,
                                              short* __restrict__ Wt,
                                              int N, int obase) {
    __shared__ __align__(16) short tile[64 * 72];
    const int kt = blockIdx.y * 64, n0 = blockIdx.x * 64;
    const int t = threadIdx.x;
    const int r = t >> 4, c4 = (t & 15) * 4;
#pragma unroll
    for (int i = 0; i < 4; i++) {
        int kr = r + i * 16;
        f4v v = *(const f4v*)&W[(long)(kt + kr) * N + n0 + c4];
#pragma unroll
        for (int j = 0; j < 4; j++) tile[(c4 + j) * 72 + kr] = f2bf(v[j]);
    }
    __syncthreads();
    const int nr = t >> 3, kc = (t & 7) * 8;
#pragma unroll
    for (int i = 0; i < 2; i++) {
        int n = nr + i * 32;
        *(s8v*)&Wt[(long)(obase + n0 + n) * 2048 + kt + kc] = *(const s8v*)&tile[n * 72 + kc];
    }
}

// m97-style GEMM: A (M x K bf16, stride lda), Bt (N x K bf16, stride ldb),
// C (M x N, stride ldc; fp32 or bf16). 128x128 tile, BK=32,
// global_load_lds width=16 staging, unpadded LDS tiles.
template <bool CF32>
__global__ __launch_bounds__(256) void gemm_bt(const short* __restrict__ A,
                                               const short* __restrict__ Bt,
                                               void* __restrict__ Cv,
                                               int K, int lda, int ldb, int ldc) {
    __shared__ __align__(16) short As[128 * 32];
    __shared__ __align__(16) short Bs[128 * 32];
    const int tid = threadIdx.x;
    const int lane = tid & 63;
    const int wave = tid >> 6;
    const int quad = lane >> 4;
    const int l15 = lane & 15;
    const int m0 = blockIdx.y * 128;
    const int n0 = blockIdx.x * 128;
    const int wm = (wave & 1) * 64;
    const int wn = (wave >> 1) * 64;

    f4v acc[4][4];
#pragma unroll
    for (int i = 0; i < 4; i++)
#pragma unroll
        for (int j = 0; j < 4; j++) acc[i][j] = (f4v){0.f, 0.f, 0.f, 0.f};

    // wave-call j stages chunks s = (j*4+wave)*64 + lane; chunk s -> row s>>2, kc (s&3)*8
    const int s0 = wave * 64 + lane, s1 = (4 + wave) * 64 + lane;
    const short* a0 = A + (long)(m0 + (s0 >> 2)) * lda + (s0 & 3) * 8;
    const short* a1 = A + (long)(m0 + (s1 >> 2)) * lda + (s1 & 3) * 8;
    const short* b0 = Bt + (long)(n0 + (s0 >> 2)) * ldb + (s0 & 3) * 8;
    const short* b1 = Bt + (long)(n0 + (s1 >> 2)) * ldb + (s1 & 3) * 8;
    char* lA0 = (char*)As + wave * 1024;
    char* lA1 = (char*)As + (4 + wave) * 1024;
    char* lB0 = (char*)Bs + wave * 1024;
    char* lB1 = (char*)Bs + (4 + wave) * 1024;

    for (int k0 = 0; k0 < K; k0 += 32) {
        __syncthreads();
        __builtin_amdgcn_global_load_lds((gp1_t)(a0 + k0), (lp3_t)lA0, 16, 0, 0);
        __builtin_amdgcn_global_load_lds((gp1_t)(a1 + k0), (lp3_t)lA1, 16, 0, 0);
        __builtin_amdgcn_global_load_lds((gp1_t)(b0 + k0), (lp3_t)lB0, 16, 0, 0);
        __builtin_amdgcn_global_load_lds((gp1_t)(b1 + k0), (lp3_t)lB1, 16, 0, 0);
        __syncthreads();
        s8v af[4], bfr[4];
#pragma unroll
        for (int mi = 0; mi < 4; mi++)
            af[mi] = *(const s8v*)(&As[(wm + mi * 16 + l15) * 32 + quad * 8]);
#pragma unroll
        for (int ni = 0; ni < 4; ni++)
            bfr[ni] = *(const s8v*)(&Bs[(wn + ni * 16 + l15) * 32 + quad * 8]);
#pragma unroll
        for (int mi = 0; mi < 4; mi++)
#pragma unroll
            for (int ni = 0; ni < 4; ni++)
                acc[mi][ni] = __builtin_amdgcn_mfma_f32_16x16x32_bf16(af[mi], bfr[ni], acc[mi][ni], 0, 0, 0);
    }
#pragma unroll
    for (int mi = 0; mi < 4; mi++)
#pragma unroll
        for (int ni = 0; ni < 4; ni++)
#pragma unroll
            for (int r = 0; r < 4; r++) {
                int row = m0 + wm + mi * 16 + quad * 4 + r;
                int col = n0 + wn + ni * 16 + l15;
                if (CF32) ((float*)Cv)[(long)row * ldc + col] = acc[mi][ni][r];
                else      ((short*)Cv)[(long)row * ldc + col] = f2bf(acc[mi][ni][r]);
            }
}

// RoPE in-place on qkv cols [0,2560)
__global__ __launch_bounds__(256) void rope_kernel(short* __restrict__ qkv) {
    int tid = blockIdx.x * 256 + threadIdx.x;
    int p = tid % 1280;
    int row = tid / 1280;
    int head = p >> 5;
    int j = p & 31;
    int s = row & 2047;
    int c1 = head * 64 + j;
    float freq = exp2f(-(float)j * 0.4152410118609203f); // log2(10000)/32
    float ang = (float)s * freq;
    float sn, cs;
    __sincosf(ang, &sn, &cs);
    long base = (long)row * 3072;
    float x1 = bf2f(qkv[base + c1]);
    float x2 = bf2f(qkv[base + c1 + 32]);
    qkv[base + c1]      = f2bf(x1 * cs - x2 * sn);
    qkv[base + c1 + 32] = f2bf(x2 * cs + x1 * sn);
}

// V transpose: qkv v-region -> Vt_g[(b*8+kvh)*64 + d][key] (ld 2048)
__global__ __launch_bounds__(256) void vtrans(const short* __restrict__ qkv,
                                              short* __restrict__ Vt_g) {
    __shared__ __align__(16) short tile[64 * 72];
    const int kt = blockIdx.x * 64;
    const int kvh = blockIdx.y;
    const int b = blockIdx.z;
    const int t = threadIdx.x;
#pragma unroll
    for (int cc = 0; cc < 2; cc++) {
        int ch = t + cc * 256;
        int key = ch >> 3, d0 = (ch & 7) * 8;
        s8v v = *(const s8v*)&qkv[(long)(b * 2048 + kt + key) * 3072 + 2560 + kvh * 64 + d0];
#pragma unroll
        for (int i = 0; i < 8; i++) tile[(d0 + i) * 72 + key] = v[i];
    }
    __syncthreads();
#pragma unroll
    for (int cc = 0; cc < 2; cc++) {
        int ch = t + cc * 256;
        int d = ch >> 3, kc = (ch & 7) * 8;
        *(s8v*)&Vt_g[(long)((b * 8 + kvh) * 64 + d) * 2048 + kt + kc] = *(const s8v*)&tile[d * 72 + kc];
    }
}

// flash attention, fixed-max exp2-domain softmax, pretransposed V.
// grid (32 q-tiles, 32 heads, 2 batch), 4 waves x 16 q-rows. In-place output.
__global__ __launch_bounds__(256) void attn2(short* __restrict__ qkv,
                                             const short* __restrict__ Vt_g) {
    __shared__ __align__(16) char smem_[28160];
    short* Qs  = (short*)smem_;             // 64*72 shorts (aliased with Ps)
    short* Ps  = (short*)smem_;             // 4 waves * 16*76 shorts
    short* Ks  = (short*)(smem_ + 9728);    // 64*72
    short* Vts = (short*)(smem_ + 18944);   // 64*72

    const int tid = threadIdx.x;
    const int lane = tid & 63;
    const int wave = tid >> 6;
    const int quad = lane >> 4;
    const int l15 = lane & 15;
    const int b = blockIdx.z;
    const int h = blockIdx.y;
    const int kvh = h >> 2;
    const int q0 = blockIdx.x * 64;

    const long qbase = ((long)b * 2048 + q0) * 3072 + h * 64;
    const long kbase = ((long)b * 2048) * 3072 + 2048 + kvh * 64;
    const long vtbase = (long)(b * 8 + kvh) * 64 * 2048;

#pragma unroll
    for (int cc = 0; cc < 2; cc++) {
        int ch = tid + cc * 256;
        int r = ch >> 3, d0 = (ch & 7) * 8;
        *(s8v*)&Qs[r * 72 + d0] = *(const s8v*)&qkv[qbase + (long)r * 3072 + d0];
    }
    __syncthreads();
    s8v qf0 = *(const s8v*)&Qs[(wave * 16 + l15) * 72 + quad * 8];
    s8v qf1 = *(const s8v*)&Qs[(wave * 16 + l15) * 72 + 32 + quad * 8];
    __syncthreads();   // Qs dead; Ps may now overwrite it

    float rs[4] = {0.f, 0.f, 0.f, 0.f};
    f4v o[4];
#pragma unroll
    for (int ni = 0; ni < 4; ni++) o[ni] = (f4v){0.f, 0.f, 0.f, 0.f};
    short* Pw = Ps + wave * 1216;  // 16*76

    for (int kt = 0; kt < 2048; kt += 64) {
        __syncthreads();
#pragma unroll
        for (int cc = 0; cc < 2; cc++) {
            int ch = tid + cc * 256;
            int r = ch >> 3, c0 = (ch & 7) * 8;
            *(s8v*)&Ks[r * 72 + c0]  = *(const s8v*)&qkv[kbase + (long)(kt + r) * 3072 + c0];
            *(s8v*)&Vts[r * 72 + c0] = *(const s8v*)&Vt_g[vtbase + (long)r * 2048 + kt + c0];
        }
        __syncthreads();

        f4v sc[4];
#pragma unroll
        for (int ni = 0; ni < 4; ni++) {
            s8v kf0 = *(const s8v*)&Ks[(ni * 16 + l15) * 72 + quad * 8];
            s8v kf1 = *(const s8v*)&Ks[(ni * 16 + l15) * 72 + 32 + quad * 8];
            f4v a = (f4v){0.f, 0.f, 0.f, 0.f};
            a = __builtin_amdgcn_mfma_f32_16x16x32_bf16(qf0, kf0, a, 0, 0, 0);
            a = __builtin_amdgcn_mfma_f32_16x16x32_bf16(qf1, kf1, a, 0, 0, 0);
            sc[ni] = a;
        }
        // p = 2^(s*0.125*log2e - 24); fixed max (scores bounded << overflow)
#pragma unroll
        for (int ni = 0; ni < 4; ni++)
#pragma unroll
            for (int r = 0; r < 4; r++) {
                float p = exp2f(fmaf(sc[ni][r], 0.18033688011112042f, -24.0f));
                rs[r] += p;
                unsigned u = __float_as_uint(p);
                Pw[(quad * 4 + r) * 76 + ni * 16 + l15] = (short)((u + 0x8000u) >> 16);
            }
        s8v pf0 = *(const s8v*)&Pw[l15 * 76 + quad * 8];
        s8v pf1 = *(const s8v*)&Pw[l15 * 76 + 32 + quad * 8];
#pragma unroll
        for (int ni = 0; ni < 4; ni++) {
            s8v vf0 = *(const s8v*)&Vts[(ni * 16 + l15) * 72 + quad * 8];
            s8v vf1 = *(const s8v*)&Vts[(ni * 16 + l15) * 72 + 32 + quad * 8];
            o[ni] = __builtin_amdgcn_mfma_f32_16x16x32_bf16(pf0, vf0, o[ni], 0, 0, 0);
            o[ni] = __builtin_amdgcn_mfma_f32_16x16x32_bf16(pf1, vf1, o[ni], 0, 0, 0);
        }
    }
    float l[4];
#pragma unroll
    for (int r = 0; r < 4; r++) {
        float v = rs[r];
        v += __shfl_xor(v, 1);
        v += __shfl_xor(v, 2);
        v += __shfl_xor(v, 4);
        v += __shfl_xor(v, 8);
        l[r] = v;
    }
#pragma unroll
    for (int r = 0; r < 4; r++) {
        float inv = 1.0f / l[r];
        int srow = q0 + wave * 16 + quad * 4 + r;
        long obase = ((long)b * 2048 + srow) * 3072 + h * 64;
#pragma unroll
        for (int ni = 0; ni < 4; ni++)
            qkv[obase + ni * 16 + l15] = f2bf(o[ni][r] * inv);
    }
}

// ======================= FALLBACK PATH (round-6, known-PASS) =======================

template <bool AF32, bool CF32>
__global__ __launch_bounds__(256) void gemm_bn(const void* __restrict__ Av,
                                               const float* __restrict__ B,
                                               void* __restrict__ Cv,
                                               int K, int N, int lda, int ldc) {
    __shared__ __align__(16) short As[128 * 40];
    __shared__ __align__(16) short Bs[128 * 40];
    const int tid = threadIdx.x;
    const int lane = tid & 63;
    const int wave = tid >> 6;
    const int quad = lane >> 4;
    const int l15 = lane & 15;
    const int m0 = blockIdx.y * 128;
    const int n0 = blockIdx.x * 128;
    const int wm = (wave & 1) * 64;
    const int wn = (wave >> 1) * 64;

    f4v acc[4][4];
#pragma unroll
    for (int i = 0; i < 4; i++)
#pragma unroll
        for (int j = 0; j < 4; j++) acc[i][j] = (f4v){0.f, 0.f, 0.f, 0.f};

    const int ar0 = tid >> 2, akc0 = (tid & 3) * 8;
    const int ar1 = (tid + 256) >> 2, akc1 = ((tid + 256) & 3) * 8;
    const int bk0 = tid >> 4, bnc0 = (tid & 15) * 8;
    const int bk1 = (tid + 256) >> 4, bnc1 = ((tid + 256) & 15) * 8;

    for (int k0 = 0; k0 < K; k0 += 32) {
        __syncthreads();
        if (AF32) {
            const float* A = (const float*)Av;
            *(s8v*)(&As[ar0 * 40 + akc0]) = cvt8(&A[(long)(m0 + ar0) * lda + k0 + akc0]);
            *(s8v*)(&As[ar1 * 40 + akc1]) = cvt8(&A[(long)(m0 + ar1) * lda + k0 + akc1]);
        } else {
            const short* A = (const short*)Av;
            *(s8v*)(&As[ar0 * 40 + akc0]) = *(const s8v*)(&A[(long)(m0 + ar0) * lda + k0 + akc0]);
            *(s8v*)(&As[ar1 * 40 + akc1]) = *(const s8v*)(&A[(long)(m0 + ar1) * lda + k0 + akc1]);
        }
        s8v b0 = cvt8(&B[(long)(k0 + bk0) * N + n0 + bnc0]);
        s8v b1 = cvt8(&B[(long)(k0 + bk1) * N + n0 + bnc1]);
#pragma unroll
        for (int i = 0; i < 8; i++) Bs[(bnc0 + i) * 40 + bk0] = b0[i];
#pragma unroll
        for (int i = 0; i < 8; i++) Bs[(bnc1 + i) * 40 + bk1] = b1[i];
        __syncthreads();
        s8v af[4], bfr[4];
#pragma unroll
        for (int mi = 0; mi < 4; mi++)
            af[mi] = *(const s8v*)(&As[(wm + mi * 16 + l15) * 40 + quad * 8]);
#pragma unroll
        for (int ni = 0; ni < 4; ni++)
            bfr[ni] = *(const s8v*)(&Bs[(wn + ni * 16 + l15) * 40 + quad * 8]);
#pragma unroll
        for (int mi = 0; mi < 4; mi++)
#pragma unroll
            for (int ni = 0; ni < 4; ni++)
                acc[mi][ni] = __builtin_amdgcn_mfma_f32_16x16x32_bf16(af[mi], bfr[ni], acc[mi][ni], 0, 0, 0);
    }
#pragma unroll
    for (int mi = 0; mi < 4; mi++)
#pragma unroll
        for (int ni = 0; ni < 4; ni++)
#pragma unroll
            for (int r = 0; r < 4; r++) {
                int row = m0 + wm + mi * 16 + quad * 4 + r;
                int col = n0 + wn + ni * 16 + l15;
                if (CF32) ((float*)Cv)[(long)row * ldc + col] = acc[mi][ni][r];
                else      ((short*)Cv)[(long)row * ldc + col] = f2bf(acc[mi][ni][r]);
            }
}

__global__ __launch_bounds__(256) void attn_kernel(short* __restrict__ qkv) {
    __shared__ __align__(16) short Qs[64 * 72];
    __shared__ __align__(16) short Ks[64 * 72];
    __shared__ __align__(16) short Vt[64 * 72];
    __shared__ __align__(16) short Ps[4][16 * 72];

    const int tid = threadIdx.x;
    const int lane = tid & 63;
    const int wave = tid >> 6;
    const int quad = lane >> 4;
    const int l15 = lane & 15;
    const int b = blockIdx.z;
    const int h = blockIdx.y;
    const int kvh = h >> 2;
    const int q0 = blockIdx.x * 64;

    const long qbase = ((long)b * 2048 + q0) * 3072 + h * 64;
    const long kbase = ((long)b * 2048) * 3072 + 2048 + kvh * 64;
    const long vbase = kbase + 512;

#pragma unroll
    for (int cc = 0; cc < 2; cc++) {
        int ch = tid + cc * 256;
        int r = ch >> 3, d0 = (ch & 7) * 8;
        *(s8v*)(&Qs[r * 72 + d0]) = *(const s8v*)(&qkv[qbase + (long)r * 3072 + d0]);
    }
    __syncthreads();
    s8v qf[2];
    qf[0] = *(const s8v*)(&Qs[(wave * 16 + l15) * 72 + quad * 8]);
    qf[1] = *(const s8v*)(&Qs[(wave * 16 + l15) * 72 + 32 + quad * 8]);

    float m_i[4], l_i[4];
    f4v o[4];
#pragma unroll
    for (int r = 0; r < 4; r++) { m_i[r] = -1e30f; l_i[r] = 0.0f; }
#pragma unroll
    for (int ni = 0; ni < 4; ni++) o[ni] = (f4v){0.f, 0.f, 0.f, 0.f};

    for (int kt = 0; kt < 2048; kt += 64) {
        __syncthreads();
#pragma unroll
        for (int cc = 0; cc < 2; cc++) {
            int ch = tid + cc * 256;
            int r = ch >> 3, d0 = (ch & 7) * 8;
            *(s8v*)(&Ks[r * 72 + d0]) = *(const s8v*)(&qkv[kbase + (long)(kt + r) * 3072 + d0]);
            s8v v = *(const s8v*)(&qkv[vbase + (long)(kt + r) * 3072 + d0]);
            int g = d0 >> 3;
            int chn = ((r >> 3) ^ g) * 8 + (r & 7);
#pragma unroll
            for (int i = 0; i < 8; i++) Vt[(d0 + i) * 72 + chn] = v[i];
        }
        __syncthreads();

        f4v sc[4];
#pragma unroll
        for (int ni = 0; ni < 4; ni++) {
            s8v kf0 = *(const s8v*)(&Ks[(ni * 16 + l15) * 72 + quad * 8]);
            s8v kf1 = *(const s8v*)(&Ks[(ni * 16 + l15) * 72 + 32 + quad * 8]);
            f4v a = (f4v){0.f, 0.f, 0.f, 0.f};
            a = __builtin_amdgcn_mfma_f32_16x16x32_bf16(qf[0], kf0, a, 0, 0, 0);
            a = __builtin_amdgcn_mfma_f32_16x16x32_bf16(qf[1], kf1, a, 0, 0, 0);
            sc[ni] = a * 0.125f;
        }
        float alpha[4], rs[4];
#pragma unroll
        for (int r = 0; r < 4; r++) {
            float v = fmaxf(fmaxf(sc[0][r], sc[1][r]), fmaxf(sc[2][r], sc[3][r]));
            v = fmaxf(v, __shfl_xor(v, 1));
            v = fmaxf(v, __shfl_xor(v, 2));
            v = fmaxf(v, __shfl_xor(v, 4));
            v = fmaxf(v, __shfl_xor(v, 8));
            float mn = fmaxf(m_i[r], v);
            alpha[r] = __expf(m_i[r] - mn);
            m_i[r] = mn;
            rs[r] = 0.f;
        }
#pragma unroll
        for (int ni = 0; ni < 4; ni++)
#pragma unroll
            for (int r = 0; r < 4; r++) {
                float pv = __expf(sc[ni][r] - m_i[r]);
                sc[ni][r] = pv;
                rs[r] += pv;
            }
#pragma unroll
        for (int r = 0; r < 4; r++) {
            float v = rs[r];
            v += __shfl_xor(v, 1);
            v += __shfl_xor(v, 2);
            v += __shfl_xor(v, 4);
            v += __shfl_xor(v, 8);
            l_i[r] = l_i[r] * alpha[r] + v;
        }
#pragma unroll
        for (int ni = 0; ni < 4; ni++)
#pragma unroll
            for (int r = 0; r < 4; r++) {
                int row = quad * 4 + r;
                int key = ni * 16 + l15;
                int chn = ((key >> 3) ^ (row >> 3)) * 8 + (key & 7);
                Ps[wave][row * 72 + chn] = f2bf(sc[ni][r]);
            }
        __syncthreads();
#pragma unroll
        for (int ni = 0; ni < 4; ni++) {
            f4v t = o[ni];
            t[0] *= alpha[0]; t[1] *= alpha[1]; t[2] *= alpha[2]; t[3] *= alpha[3];
            o[ni] = t;
        }
        s8v pf0 = *(const s8v*)(&Ps[wave][l15 * 72 + ((quad ^ (l15 >> 3)) * 8)]);
        s8v pf1 = *(const s8v*)(&Ps[wave][l15 * 72 + (((4 + quad) ^ (l15 >> 3)) * 8)]);
#pragma unroll
        for (int ni = 0; ni < 4; ni++) {
            int d = ni * 16 + l15;
            s8v vf0 = *(const s8v*)(&Vt[d * 72 + ((quad ^ (d >> 3)) * 8)]);
            s8v vf1 = *(const s8v*)(&Vt[d * 72 + (((4 + quad) ^ (d >> 3)) * 8)]);
            o[ni] = __builtin_amdgcn_mfma_f32_16x16x32_bf16(pf0, vf0, o[ni], 0, 0, 0);
            o[ni] = __builtin_amdgcn_mfma_f32_16x16x32_bf16(pf1, vf1, o[ni], 0, 0, 0);
        }
    }
#pragma unroll
    for (int r = 0; r < 4; r++) {
        float inv = 1.0f / l_i[r];
        int srow = q0 + wave * 16 + quad * 4 + r;
        long obase = ((long)b * 2048 + srow) * 3072 + h * 64;
#pragma unroll
        for (int ni = 0; ni < 4; ni++)
            qkv[obase + ni * 16 + l15] = f2bf(o[ni][r] * inv);
    }
}

extern "C" void kernel_launch(void* const* d_in, const int* in_sizes, int n_in,
                              void* d_out, int out_size, void* d_ws, size_t ws_size,
                              hipStream_t stream) {
    (void)in_sizes; (void)n_in; (void)out_size;
    const float* x  = (const float*)d_in[0];
    const float* Wq = (const float*)d_in[1];
    const float* Wk = (const float*)d_in[2];
    const float* Wv = (const float*)d_in[3];
    const float* Wo = (const float*)d_in[4];

    const size_t need = 67108864ULL; // 64 MiB
    if (ws_size >= need) {
        short* xb    = (short*)d_ws;              // 4096x2048
        short* Wqkvt = xb + 8388608;              // 3072x2048
        short* Wot   = Wqkvt + 6291456;           // 2048x2048
        short* qkv   = Wot + 4194304;             // 4096x3072
        short* Vt_g  = qkv + 12582912;            // 16x64x2048

        cvt_x<<<4096, 256, 0, stream>>>(x, xb);
        cvt_wt<<<dim3(32, 32), 256, 0, stream>>>(Wq, Wqkvt, 2048, 0);
        cvt_wt<<<dim3(8, 32), 256, 0, stream>>>(Wk, Wqkvt, 512, 2048);
        cvt_wt<<<dim3(8, 32), 256, 0, stream>>>(Wv, Wqkvt, 512, 2560);
        cvt_wt<<<dim3(32, 32), 256, 0, stream>>>(Wo, Wot, 2048, 0);
        gemm_bt<false><<<dim3(24, 32), 256, 0, stream>>>(xb, Wqkvt, qkv, 2048, 2048, 2048, 3072);
        rope_kernel<<<dim3(20480), 256, 0, stream>>>(qkv);
        vtrans<<<dim3(32, 8, 2), 256, 0, stream>>>(qkv, Vt_g);
        attn2<<<dim3(32, 32, 2), 256, 0, stream>>>(qkv, Vt_g);
        gemm_bt<true><<<dim3(16, 32), 256, 0, stream>>>(qkv, Wot, d_out, 2048, 3072, 2048, 2048);
    } else {
        short* qkv = (short*)d_ws;
        gemm_bn<true, false><<<dim3(16, 32), 256, 0, stream>>>(x, Wq, qkv,        2048, 2048, 2048, 3072);
        gemm_bn<true, false><<<dim3(4, 32), 256, 0, stream>>>(x, Wk, qkv + 2048, 2048,  512, 2048, 3072);
        gemm_bn<true, false><<<dim3(4, 32), 256, 0, stream>>>(x, Wv, qkv + 2560, 2048,  512, 2048, 3072);
        rope_kernel<<<dim3(20480), 256, 0, stream>>>(qkv);
        attn_kernel<<<dim3(32, 32, 2), 256, 0, stream>>>(qkv);
        gemm_bn<false, true><<<dim3(16, 32), 256, 0, stream>>>(qkv, Wo, d_out, 2048, 2048, 3072, 2048);
    }
}